// Round 4
// baseline (366.539 us; speedup 1.0000x reference)
//
#include <hip/hip_runtime.h>
#include <cmath>

// ---------------------------------------------------------------------------
// Round 15: 4M x 2N wave grid + rotating B-banks + COUNTED lgkm waits.
//   - wave owns 64 rows x 128 cols (acc[4][8], same 128 AGPR)
//   - A read ONCE per K-tile (af[4][2], 8 ds_read) -> no intra-tile A WAR
//   - B in two banks bfE/bfO; quadrant c issues bank-(c+1) reads then waits
//     s_waitcnt lgkmcnt(4): current bank ready, next bank in flight UNDER
//     the 16-MFMA cluster (true LDS/matrix-pipe overlap; rounds 13/14 used
//     lgkmcnt(0) full drains -> pipes alternated, MfmaUtil stuck at 38%)
//   - 2 barriers/tile: BAR#1 (all reads of cur buffers done -> stage safe),
//     BAR#2 (VMW(8) -> next buffers valid -> boundary reads af'/bf0')
//   - staging, xor-octet swizzle, XCD-pinned mapping (FETCH 104MB): unchanged
// Arena (inside attention output region): slot r (16 KB) =
//   [ G-bf16 row r : 8 KB | input bf16 chunks 4r..4r+3 : 8 KB ]
// chunk order: 0..N-1 step, N..N+M-1 modal, N+M..N+2M-1 negs.
// ---------------------------------------------------------------------------

#define WAVE 64

typedef __bf16 bf16x8_t __attribute__((ext_vector_type(8)));
typedef __bf16 bf16x4_t __attribute__((ext_vector_type(4)));
typedef float f32x4_t __attribute__((ext_vector_type(4)));

__device__ __forceinline__ float wave_reduce_sum(float v) {
#pragma unroll
    for (int o = 32; o > 0; o >>= 1) v += __shfl_down(v, o, WAVE);
    return v;
}
__device__ __forceinline__ float wave_reduce_max(float v) {
#pragma unroll
    for (int o = 32; o > 0; o >>= 1) v = fmaxf(v, __shfl_down(v, o, WAVE));
    return v;
}
__device__ __forceinline__ float wave_reduce_min(float v) {
#pragma unroll
    for (int o = 32; o > 0; o >>= 1) v = fminf(v, __shfl_down(v, o, WAVE));
    return v;
}

// monotone float <-> uint map for atomicMax on floats of any sign
__device__ __forceinline__ unsigned enc_f(float f) {
    unsigned u = __float_as_uint(f);
    return (u & 0x80000000u) ? ~u : (u | 0x80000000u);
}
__device__ __forceinline__ float dec_f(unsigned e) {
    unsigned u = (e & 0x80000000u) ? (e & 0x7fffffffu) : ~e;
    return __uint_as_float(u);
}

// ---------------- convert fp32 -> bf16 chunks + inverse norms --------------
// one row per WAVE (4 rows/block), no block barriers.
__global__ __launch_bounds__(256)
void convert_norms_kernel(const float* __restrict__ step,
                          const float* __restrict__ modal,
                          const float* __restrict__ negs,
                          char* __restrict__ arena,
                          float* __restrict__ ina, float* __restrict__ inb,
                          float* __restrict__ inn,
                          unsigned* __restrict__ negmax_u, int N, int M) {
    const int tid = threadIdx.x, lane = tid & 63, wv = tid >> 6;
    const int b = blockIdx.x * 4 + wv;
    const float* src;
    if (b < N)          src = step  + (size_t)b * 1024;
    else if (b < N + M) src = modal + (size_t)(b - N) * 1024;
    else                src = negs  + (size_t)(b - N - M) * 1024;

    char* cb = arena + (((size_t)(b >> 2)) << 14) + ((size_t)(b & 3) << 11) + 8192;
    float s = 0.0f;
#pragma unroll
    for (int q = 0; q < 4; q++) {
        const int idx = lane + q * 64;
        const float4 v = ((const float4*)src)[idx];
        bf16x4_t o;
        o[0] = (__bf16)v.x; o[1] = (__bf16)v.y;
        o[2] = (__bf16)v.z; o[3] = (__bf16)v.w;
        *(bf16x4_t*)(cb + (size_t)idx * 8) = o;
        s += v.x * v.x + v.y * v.y + v.z * v.z + v.w * v.w;
    }
    s = wave_reduce_sum(s);
    if (lane == 0) {
        const float inv = 1.0f / fmaxf(sqrtf(s), 1e-8f);
        if (b < N)          { ina[b] = inv; negmax_u[b] = 0u; }
        else if (b < N + M) inb[b - N] = inv;
        else                inn[b - N - M] = inv;
    }
}

// ---------------- fused bf16 MFMA GEMM, counted-lgkm pipeline --------------
#define GLD16(g, l)                                                       \
    __builtin_amdgcn_global_load_lds(                                     \
        (const __attribute__((address_space(1))) void*)(g),               \
        (__attribute__((address_space(3))) void*)(l), 16, 0, 0)

#define BAR()     asm volatile("s_barrier" ::: "memory")
#define LGKMC(n)  asm volatile("s_waitcnt lgkmcnt(" #n ")" ::: "memory")
#define VMW(n)    asm volatile("s_waitcnt vmcnt(" #n ")" ::: "memory")
#define SB0()     __builtin_amdgcn_sched_barrier(0)

#define STAGE_A(Ab, kt)                                                   \
    _Pragma("unroll")                                                     \
    for (int h = 0; h < 2; h++)                                           \
    _Pragma("unroll")                                                     \
      for (int c = 0; c < 2; c++)                                         \
        GLD16(arena + srcA[h][c] + (size_t)(kt) * 128,                    \
              (Ab) + h * 8192 + c * 4096 + w * 512);

#define STAGE_B(Bb, kt)                                                   \
    _Pragma("unroll")                                                     \
    for (int h = 0; h < 2; h++)                                           \
    _Pragma("unroll")                                                     \
      for (int c = 0; c < 2; c++)                                         \
        GLD16(arena + srcB[h][c] + (size_t)(kt) * 128,                    \
              (Bb) + h * 8192 + c * 4096 + w * 512);

// A fragments: all 64 wave rows, read once per K-tile (8 x ds_read_b128)
#define READ_AF(Ab)                                                       \
    _Pragma("unroll")                                                     \
    for (int ii = 0; ii < 4; ii++)                                        \
    _Pragma("unroll")                                                     \
      for (int kk = 0; kk < 2; kk++)                                      \
        af[ii][kk] = *(const bf16x8_t*)&(Ab)[arow0 + ii * 1024 +          \
                                             koff[kk]];

// B fragments for column-quadrant c into bank dst (4 x ds_read_b128)
#define READ_BF(dst, c, Bb)                                               \
    _Pragma("unroll")                                                     \
    for (int jj = 0; jj < 2; jj++)                                        \
    _Pragma("unroll")                                                     \
      for (int kk = 0; kk < 2; kk++)                                      \
        dst[jj][kk] = *(const bf16x8_t*)&(Bb)[brow0 + (c) * 2048 +        \
                                              jj * 1024 + koff[kk]];

// 16 MFMA for column-quadrant c using B-bank `bank`
#define MFMA_Q(c, bank)                                                   \
    __builtin_amdgcn_s_setprio(1);                                        \
    _Pragma("unroll")                                                     \
    for (int kk = 0; kk < 2; kk++)                                        \
    _Pragma("unroll")                                                     \
      for (int ii = 0; ii < 4; ii++)                                      \
      _Pragma("unroll")                                                   \
        for (int jj = 0; jj < 2; jj++)                                    \
          acc[ii][(c) * 2 + jj] =                                         \
              __builtin_amdgcn_mfma_f32_16x16x32_bf16(                    \
                  af[ii][kk], bank[jj][kk], acc[ii][(c) * 2 + jj],        \
                  0, 0, 0);                                               \
    __builtin_amdgcn_s_setprio(0);

// one K-tile: Q0..Q3 with next-bank reads in flight under each cluster
// (counted lgkm); 2 barriers at the boundary only.
#define TILE(Ac, Bc, An, Bn, ktpre, pre, rd)                              \
    READ_BF(bfO, 1, Bc);                                                  \
    LGKMC(4); SB0();          /* af+bf0 done; bf1 in flight */            \
    MFMA_Q(0, bfE);                                                       \
    READ_BF(bfE, 2, Bc);                                                  \
    LGKMC(4); SB0();          /* bf1 done; bf2 in flight */               \
    MFMA_Q(1, bfO);                                                       \
    READ_BF(bfO, 3, Bc);                                                  \
    LGKMC(4); SB0();          /* bf2 done; bf3 in flight */               \
    MFMA_Q(2, bfE);                                                       \
    LGKMC(0); SB0();          /* bf3 done */                              \
    MFMA_Q(3, bfO);                                                       \
    if (rd) {                                                             \
        BAR();                /* all waves' Ac/Bc reads complete */       \
        if (pre) { STAGE_A(Ac, ktpre); STAGE_B(Bc, ktpre); VMW(8); }      \
        else     { VMW(0); }                                              \
        BAR();                /* An/Bn fully staged */                    \
        READ_AF(An);          /* 12 boundary reads under Q3 drain */      \
        READ_BF(bfE, 0, Bn);                                              \
    }

__global__ __launch_bounds__(512, 2)
void gemm_fused_kernel(char* __restrict__ arena, int N, int M,
                       const float* __restrict__ inv_nn,
                       unsigned* __restrict__ negmax_u) {
    __shared__ __bf16 As[2][256 * 64];   // 2 x 32 KB
    __shared__ __bf16 Bs[2][256 * 64];   // 2 x 32 KB  (total 128 KB)

    // XCD-pinned A-stripe mapping (1 block/CU, 32 CU/XCD, round-robin disp):
    //   xcd = lin&7 owns A-panels 4*xcd..4*xcd+3 (2MB, resident all rounds)
    //   j = lin>>3: round r = j>>5 picks 8 B-panels; u = j&31: 4bm x 8bn
    const int lin = blockIdx.x;
    const int xcd = lin & 7;
    const int j   = lin >> 3;
    const int r   = j >> 5;
    const int u   = j & 31;
    const int bm = ((xcd << 2) + (u & 3)) << 8;
    const int bn = ((r << 3) + (u >> 2)) << 8;

    const int t = threadIdx.x, w = t >> 6, lane = t & 63;
    const int lane16 = lane & 15, lq = lane >> 4;
    const int wm = w & 3, wn = w >> 2;          // 4 M-waves x 2 N-waves

    // ---- staging source offsets (bytes from arena; xor-swizzled octet) ----
    const int l3 = lane >> 3, ol = lane & 7;
    const int og = ol ^ l3;                      // (grow&7)==l3 for all rows
    unsigned srcA[2][2], srcB[2][2];
#pragma unroll
    for (int h = 0; h < 2; h++)
#pragma unroll
      for (int c = 0; c < 2; c++) {
        const int ga = bm + h * 128 + c * 64 + w * 8 + l3;
        srcA[h][c] = ((unsigned)(ga >> 2) << 14) + ((unsigned)(ga & 3) << 11)
                     + 8192u + (unsigned)og * 16u;
        const int gb = N + bn + h * 128 + c * 64 + w * 8 + l3;
        srcB[h][c] = ((unsigned)(gb >> 2) << 14) + ((unsigned)(gb & 3) << 11)
                     + 8192u + (unsigned)og * 16u;
      }

    // ---- fragment read offsets (swizzled octet, elements) ----
    const int sxr = lane16 & 7;
    int koff[2];
#pragma unroll
    for (int kk = 0; kk < 2; kk++) koff[kk] = ((lq + 4 * kk) ^ sxr) * 8;
    const int arow0 = wm * 4096 + lane16 * 64;   // wave's A rows: wm*64+..
    const int brow0 = wn * 8192 + lane16 * 64;   // wave's B cols: wn*128+..

    f32x4_t acc[4][8];
#pragma unroll
    for (int i = 0; i < 4; i++)
#pragma unroll
      for (int j2 = 0; j2 < 8; j2++) acc[i][j2] = (f32x4_t){0.f, 0.f, 0.f, 0.f};

    bf16x8_t af[4][2], bfE[2][2], bfO[2][2];

    __bf16* const A0 = As[0]; __bf16* const A1 = As[1];
    __bf16* const B0 = Bs[0]; __bf16* const B1 = Bs[1];

    // prologue: tiles 0,1 staged; tile0 landed; af + bf0 issued
    STAGE_A(A0, 0); STAGE_B(B0, 0);
    STAGE_A(A1, 1); STAGE_B(B1, 1);
    VMW(8);
    BAR();
    READ_AF(A0);
    READ_BF(bfE, 0, B0);

    for (int it = 0; it < 8; ++it) {
        const int pre = (it < 7);
        const int k2 = 2 * it + 2, k3 = 2 * it + 3;
        TILE(A0, B0, A1, B1, k2, pre, 1)
        TILE(A1, B1, A0, B0, k3, pre, pre)
    }

    // C/D layout (16x16x32): col = lane16, row = lq*4 + reg
    if (bn < M) {
        // modal half: store G as bf16 into slot front halves
#pragma unroll
        for (int i = 0; i < 4; i++) {
#pragma unroll
            for (int rr = 0; rr < 4; rr++) {
                const int grow = bm + wm * 64 + i * 16 + lq * 4 + rr;
                __bf16* dst = (__bf16*)(arena + ((size_t)grow << 14)) +
                              bn + wn * 128 + lane16;
#pragma unroll
                for (int jj = 0; jj < 8; jj++)
                    dst[jj * 16] = (__bf16)acc[i][jj][rr];
            }
        }
    } else {
        // negatives half: per-row cosine max via atomicMax
        float invn[8];
#pragma unroll
        for (int jj = 0; jj < 8; jj++)
            invn[jj] = inv_nn[(bn - M) + wn * 128 + jj * 16 + lane16];
#pragma unroll
        for (int i = 0; i < 4; i++) {
#pragma unroll
            for (int rr = 0; rr < 4; rr++) {
                float v = acc[i][0][rr] * invn[0];
#pragma unroll
                for (int jj = 1; jj < 8; jj++)
                    v = fmaxf(v, acc[i][jj][rr] * invn[jj]);
#pragma unroll
                for (int o = 8; o > 0; o >>= 1)
                    v = fmaxf(v, __shfl_xor(v, o, WAVE));
                if (lane16 == 0)
                    atomicMax(&negmax_u[bm + wm * 64 + i * 16 + lq * 4 + rr],
                              enc_f(v));
            }
        }
    }
}

// ---------------- softmax with fp32 fix-up, coalesced layout ---------------
#define CUT 2.0f
#define MAXCAND 64

__global__ __launch_bounds__(256)
void softmax_fix_kernel(char* __restrict__ arena, const float* __restrict__ step,
                        const float* __restrict__ modal,
                        const float* __restrict__ ina, const float* __restrict__ inb,
                        float* __restrict__ perstep, float* __restrict__ wout,
                        float* __restrict__ attn) {
    const int row = blockIdx.x, tid = threadIdx.x;
    const int lane = tid & 63, wv = tid >> 6;

    __shared__ float srow_s[1024];
    __shared__ float red[8];
    __shared__ float bcast[2];
    __shared__ int   cand[MAXCAND];
    __shared__ float exact[MAXCAND];
    __shared__ int   cnt;

    if (tid == 0) cnt = 0;
    ((float4*)srow_s)[tid] = ((const float4*)(step + (size_t)row * 1024))[tid];

    const __bf16* gb = (const __bf16*)(arena + ((size_t)row << 14));
    float vals[16];
    float invn[16];
#pragma unroll
    for (int g = 0; g < 4; g++) {
        const bf16x4_t v = *(const bf16x4_t*)(gb + g * 1024 + tid * 4);
        const float4 x = *(const float4*)(inb + g * 1024 + tid * 4);
        vals[g * 4 + 0] = (float)v[0]; vals[g * 4 + 1] = (float)v[1];
        vals[g * 4 + 2] = (float)v[2]; vals[g * 4 + 3] = (float)v[3];
        invn[g * 4 + 0] = x.x; invn[g * 4 + 1] = x.y;
        invn[g * 4 + 2] = x.z; invn[g * 4 + 3] = x.w;
    }

    float dmax = -3.4e38f;
#pragma unroll
    for (int j = 0; j < 16; j++) dmax = fmaxf(dmax, vals[j]);
    float wm = wave_reduce_max(dmax);
    if (lane == 0) red[wv] = wm;
    __syncthreads();   // also covers cnt=0 and srow_s
    if (tid == 0) bcast[0] = fmaxf(fmaxf(red[0], red[1]), fmaxf(red[2], red[3]));
    __syncthreads();
    const float m0 = bcast[0];

    const float thr = m0 - CUT;
#pragma unroll
    for (int g = 0; g < 4; g++)
#pragma unroll
        for (int u = 0; u < 4; u++) {
            if (vals[g * 4 + u] >= thr) {
                const int pos = atomicAdd(&cnt, 1);
                if (pos < MAXCAND) cand[pos] = g * 1024 + tid * 4 + u;
            }
        }
    __syncthreads();
    const int nc = min(cnt, MAXCAND);

    // exact fp32 dots, one candidate per wave
    for (int i = wv; i < nc; i += 4) {
        const float* mrow = modal + (size_t)cand[i] * 1024;
        float p = 0.0f;
#pragma unroll
        for (int q = 0; q < 16; q++) {
            const int idx = lane + q * 64;
            p = fmaf(srow_s[idx], mrow[idx], p);
        }
        p = wave_reduce_sum(p);
        if (lane == 0) exact[i] = p;
    }
    __syncthreads();

    for (int i = 0; i < nc; i++) {
        const int c = cand[i];
        if (((c & 1023) >> 2) == tid) vals[(c >> 10) * 4 + (c & 3)] = exact[i];
    }

    float dmax2 = -3.4e38f, cmax = -3.4e38f;
#pragma unroll
    for (int j = 0; j < 16; j++) {
        dmax2 = fmaxf(dmax2, vals[j]);
        cmax = fmaxf(cmax, vals[j] * invn[j]);
    }
    float wg = wave_reduce_max(dmax2);
    float wc = wave_reduce_max(cmax);
    if (lane == 0) { red[wv] = wg; red[4 + wv] = wc; }
    __syncthreads();
    if (tid == 0) {
        bcast[0] = fmaxf(fmaxf(red[0], red[1]), fmaxf(red[2], red[3]));
        bcast[1] = fmaxf(fmaxf(red[4], red[5]), fmaxf(red[6], red[7]));
    }
    __syncthreads();
    const float invT = 1.0f / 0.07f;
    const float mlog = bcast[0] * invT;
    const float cmaxAll = bcast[1];

    float evals[16];
    float lsum = 0.0f;
#pragma unroll
    for (int j = 0; j < 16; j++) {
        const float e = __expf(vals[j] * invT - mlog);
        evals[j] = e;
        lsum += e;
    }
    lsum = wave_reduce_sum(lsum);
    __syncthreads();
    if (lane == 0) red[wv] = lsum;
    __syncthreads();
    if (tid == 0) bcast[0] = red[0] + red[1] + red[2] + red[3];
    __syncthreads();
    const float invZ = 1.0f / bcast[0];

    float* arow = attn + (size_t)row * 4096;
    float wacc = 0.0f;
#pragma unroll
    for (int g = 0; g < 4; g++) {
        float4 o;
        const float a0 = evals[g * 4 + 0] * invZ, a1 = evals[g * 4 + 1] * invZ;
        const float a2 = evals[g * 4 + 2] * invZ, a3 = evals[g * 4 + 3] * invZ;
        o.x = a0; o.y = a1; o.z = a2; o.w = a3;
        *(float4*)(arow + g * 1024 + tid * 4) = o;
        wacc += a0 * vals[g * 4 + 0] * invn[g * 4 + 0];
        wacc += a1 * vals[g * 4 + 1] * invn[g * 4 + 1];
        wacc += a2 * vals[g * 4 + 2] * invn[g * 4 + 2];
        wacc += a3 * vals[g * 4 + 3] * invn[g * 4 + 3];
    }
    wacc = wave_reduce_sum(wacc);
    __syncthreads();
    if (lane == 0) red[wv] = wacc;
    __syncthreads();
    if (tid == 0) {
        const float inv_na = ina[row];
        perstep[row] = cmaxAll * inv_na;
        wout[row] = (red[0] + red[1] + red[2] + red[3]) * inv_na;
    }
}

// ---------------- finalize scalars -----------------------------------------
__global__ __launch_bounds__(1024)
void finalize_kernel(const float* __restrict__ perstep, const float* __restrict__ w,
                     const unsigned* __restrict__ negmax_u,
                     const float* __restrict__ ina, float* __restrict__ out,
                     int N, size_t NM) {
    float s_a = 0.0f, s_w = 0.0f, s_n = 0.0f, mn = 3.4e38f;
    for (int i = threadIdx.x; i < N; i += 1024) {
        const float p = perstep[i];
        s_a += p;
        s_w += w[i];
        s_n += dec_f(negmax_u[i]) * ina[i];
        mn = fminf(mn, p);
    }
    s_a = wave_reduce_sum(s_a);
    s_w = wave_reduce_sum(s_w);
    s_n = wave_reduce_sum(s_n);
    mn  = wave_reduce_min(mn);
    __shared__ float ra[16], rw[16], rn[16], rm[16];
    const int lane = threadIdx.x & 63, wv = threadIdx.x >> 6;
    if (lane == 0) { ra[wv] = s_a; rw[wv] = s_w; rn[wv] = s_n; rm[wv] = mn; }
    __syncthreads();
    if (threadIdx.x == 0) {
        float ta = 0, tw = 0, tn = 0, tm = 3.4e38f;
#pragma unroll
        for (int i = 0; i < 16; i++) {
            ta += ra[i]; tw += rw[i]; tn += rn[i]; tm = fminf(tm, rm[i]);
        }
        const float inv = 1.0f / (float)N;
        const float alignment = ta * inv;
        const float weighted  = tw * inv;
        const float neg       = tn * inv;
        const float contrast  = alignment - neg;
        const float margin    = fmaxf(contrast - 0.2f, 0.0f);
        const float overall   = 0.7f * weighted + 0.3f * contrast;
        out[0] = alignment;
        out[1] = weighted;
        float* p = out + 2 + NM;
        p[0] = contrast;
        p[1] = margin;
        p[2] = alignment;   // positive_alignment
        p[3] = neg;
        p[4 + N] = tm;      // min_step_coherence
        p[5 + N] = overall;
    }
}

// ---------------------------------------------------------------------------
extern "C" void kernel_launch(void* const* d_in, const int* in_sizes, int n_in,
                              void* d_out, int out_size, void* d_ws, size_t ws_size,
                              hipStream_t stream) {
    const float* step  = (const float*)d_in[0];
    const float* modal = (const float*)d_in[1];
    const float* negs  = (const float*)d_in[2];
    float* out = (float*)d_out;

    const int K = 1024;
    const int N = in_sizes[0] / K;   // 8192
    const int M = in_sizes[1] / K;   // 4096
    const size_t NM = (size_t)N * (size_t)M;

    float* ina        = (float*)d_ws;          // N
    float* inb        = ina + N;               // M
    float* inn        = inb + M;               // M
    unsigned* negmax  = (unsigned*)(inn + M);  // N
    float* wsum       = (float*)(negmax + N);  // N

    char* arena    = (char*)d_out + 16;
    float* attn    = out + 2;
    float* perstep = out + 2 + NM + 4;

    // 1. convert inputs to bf16 chunks + inverse norms + init atomics
    convert_norms_kernel<<<(N + 2 * M) / 4, 256, 0, stream>>>(
        step, modal, negs, arena, ina, inb, inn, negmax, N, M);

    // 2. fused GEMM, counted-lgkm pipeline, XCD-pinned A-stripe mapping
    const int nblocks = (N >> 8) * ((2 * M) >> 8);   // 32 x 32 = 1024
    gemm_fused_kernel<<<nblocks, 512, 0, stream>>>(arena, N, M, inn, negmax);

    // 3. softmax + exact fp32 fix-up, writes fp32 attention + per-row outs
    softmax_fix_kernel<<<N, 256, 0, stream>>>(arena, step, modal, ina, inb,
                                              perstep, wsum, attn);

    // 4. scalars
    finalize_kernel<<<1, 1024, 0, stream>>>(perstep, wsum, negmax, ina, out, N, NM);
}

// Round 5
// 353.006 us; speedup vs baseline: 1.0383x; 1.0383x over previous
//
#include <hip/hip_runtime.h>
#include <cmath>

// ---------------------------------------------------------------------------
// Round 16: GEMM reverted to round-14 exactly (best measured: 158.9us).
// Softmax restructured for latency amortization (it's ~150us, as big as GEMM,
// at only ~25% of its HBM roofline):
//   - 4 rows per block (grid N/4): invn[16] (16KB fp32 inb) loaded ONCE
//   - post-fix max = thread-0 scan of exact[] (== old full reduce: any
//     non-candidate bf16 val < m0-2.0 < max(exact) >= m0-0.13)
//   - cmax fused into the exp/lsum reduction round
//   - evals[] dropped; exp recomputed at write (deterministic -> bitwise same)
//   -> fewer barriers/row (11->7), lower VGPR -> more blocks/CU
// Arena (inside attention output region): slot r (16 KB) =
//   [ G-bf16 row r : 8 KB | input bf16 chunks 4r..4r+3 : 8 KB ]
// chunk order: 0..N-1 step, N..N+M-1 modal, N+M..N+2M-1 negs.
// ---------------------------------------------------------------------------

#define WAVE 64

typedef __bf16 bf16x8_t __attribute__((ext_vector_type(8)));
typedef __bf16 bf16x4_t __attribute__((ext_vector_type(4)));
typedef float f32x4_t __attribute__((ext_vector_type(4)));

__device__ __forceinline__ float wave_reduce_sum(float v) {
#pragma unroll
    for (int o = 32; o > 0; o >>= 1) v += __shfl_down(v, o, WAVE);
    return v;
}
__device__ __forceinline__ float wave_reduce_max(float v) {
#pragma unroll
    for (int o = 32; o > 0; o >>= 1) v = fmaxf(v, __shfl_down(v, o, WAVE));
    return v;
}
__device__ __forceinline__ float wave_reduce_min(float v) {
#pragma unroll
    for (int o = 32; o > 0; o >>= 1) v = fminf(v, __shfl_down(v, o, WAVE));
    return v;
}

// monotone float <-> uint map for atomicMax on floats of any sign
__device__ __forceinline__ unsigned enc_f(float f) {
    unsigned u = __float_as_uint(f);
    return (u & 0x80000000u) ? ~u : (u | 0x80000000u);
}
__device__ __forceinline__ float dec_f(unsigned e) {
    unsigned u = (e & 0x80000000u) ? (e & 0x7fffffffu) : ~e;
    return __uint_as_float(u);
}

// ---------------- convert fp32 -> bf16 chunks + inverse norms --------------
// one row per WAVE (4 rows/block), no block barriers.
__global__ __launch_bounds__(256)
void convert_norms_kernel(const float* __restrict__ step,
                          const float* __restrict__ modal,
                          const float* __restrict__ negs,
                          char* __restrict__ arena,
                          float* __restrict__ ina, float* __restrict__ inb,
                          float* __restrict__ inn,
                          unsigned* __restrict__ negmax_u, int N, int M) {
    const int tid = threadIdx.x, lane = tid & 63, wv = tid >> 6;
    const int b = blockIdx.x * 4 + wv;
    const float* src;
    if (b < N)          src = step  + (size_t)b * 1024;
    else if (b < N + M) src = modal + (size_t)(b - N) * 1024;
    else                src = negs  + (size_t)(b - N - M) * 1024;

    char* cb = arena + (((size_t)(b >> 2)) << 14) + ((size_t)(b & 3) << 11) + 8192;
    float s = 0.0f;
#pragma unroll
    for (int q = 0; q < 4; q++) {
        const int idx = lane + q * 64;
        const float4 v = ((const float4*)src)[idx];
        bf16x4_t o;
        o[0] = (__bf16)v.x; o[1] = (__bf16)v.y;
        o[2] = (__bf16)v.z; o[3] = (__bf16)v.w;
        *(bf16x4_t*)(cb + (size_t)idx * 8) = o;
        s += v.x * v.x + v.y * v.y + v.z * v.z + v.w * v.w;
    }
    s = wave_reduce_sum(s);
    if (lane == 0) {
        const float inv = 1.0f / fmaxf(sqrtf(s), 1e-8f);
        if (b < N)          { ina[b] = inv; negmax_u[b] = 0u; }
        else if (b < N + M) inb[b - N] = inv;
        else                inn[b - N - M] = inv;
    }
}

// ---------------- fused bf16 MFMA GEMM (round-14 schedule, unchanged) ------
#define GLD16(g, l)                                                       \
    __builtin_amdgcn_global_load_lds(                                     \
        (const __attribute__((address_space(1))) void*)(g),               \
        (__attribute__((address_space(3))) void*)(l), 16, 0, 0)

#define BAR()   asm volatile("s_barrier" ::: "memory")
#define LGKM0() asm volatile("s_waitcnt lgkmcnt(0)" ::: "memory")
#define VMW(n)  asm volatile("s_waitcnt vmcnt(" #n ")" ::: "memory")

#define STAGE_A(Ab, kt)                                                   \
    _Pragma("unroll")                                                     \
    for (int h = 0; h < 2; h++)                                           \
    _Pragma("unroll")                                                     \
      for (int c = 0; c < 2; c++)                                         \
        GLD16(arena + srcA[h][c] + (size_t)(kt) * 128,                    \
              (Ab) + h * 8192 + c * 4096 + w * 512);

#define STAGE_B(Bb, kt)                                                   \
    _Pragma("unroll")                                                     \
    for (int h = 0; h < 2; h++)                                           \
    _Pragma("unroll")                                                     \
      for (int c = 0; c < 2; c++)                                         \
        GLD16(arena + srcB[h][c] + (size_t)(kt) * 128,                    \
              (Bb) + h * 8192 + c * 4096 + w * 512);

#define READ_A(g, Ab)                                                     \
    _Pragma("unroll")                                                     \
    for (int ii = 0; ii < 4; ii++)                                        \
    _Pragma("unroll")                                                     \
      for (int kk = 0; kk < 2; kk++)                                      \
        af[ii][kk] = *(const bf16x8_t*)&(Ab)[arow0 + (g) * 4096 +         \
                                             ii * 1024 + koff[kk]];

#define READ_B(j0, dst, Bb)                                               \
    _Pragma("unroll")                                                     \
    for (int jj = 0; jj < 2; jj++)                                        \
    _Pragma("unroll")                                                     \
      for (int kk = 0; kk < 2; kk++)                                      \
        dst[jj][kk] = *(const bf16x8_t*)&(Bb)[brow0 + ((j0) + jj) * 1024 +\
                                              koff[kk]];

#define READ_B01(Bb) READ_B(0, bf01, Bb)
#define READ_B23(Bb) READ_B(2, bf23, Bb)

#define MFMA_Q(i0, j0, bsrc)                                              \
    __builtin_amdgcn_s_setprio(1);                                        \
    _Pragma("unroll")                                                     \
    for (int kk = 0; kk < 2; kk++)                                        \
    _Pragma("unroll")                                                     \
      for (int ii = 0; ii < 4; ii++)                                      \
      _Pragma("unroll")                                                   \
        for (int jj = 0; jj < 2; jj++)                                    \
          acc[(i0) + ii][(j0) + jj] =                                     \
              __builtin_amdgcn_mfma_f32_16x16x32_bf16(                    \
                  af[ii][kk], bsrc[jj][kk], acc[(i0) + ii][(j0) + jj],    \
                  0, 0, 0);                                               \
    __builtin_amdgcn_s_setprio(0);

// one K-tile: 4 MFMA quadrants; reads for quadrant q+1 issued right after
// quadrant q's cluster (LDS pipe runs under matrix-pipe execution shadow).
// 3 barriers/tile: BAR_c (B-reads done), BAR_e (A-reads done), BAR_g (vmcnt).
#define TILE(Ac, Bc, An, Bn, ktpre, pre, rd)                              \
    LGKM0();               /* af_g0 + bf01 (boundary reads) ready */      \
    MFMA_Q(0, 0, bf01);                                                   \
    READ_B23(Bc);          /* 4 reads under MFMA1 exec */                 \
    LGKM0();                                                              \
    MFMA_Q(0, 2, bf23);                                                   \
    READ_A(1, Ac);         /* 8 reads under MFMA2 exec (af bank reuse) */ \
    BAR();                 /* BAR_c: all waves' B-reads complete */       \
    if (pre) { STAGE_B(Bc, ktpre); }                                      \
    LGKM0();               /* af_g1 ready */                              \
    MFMA_Q(4, 0, bf01);                                                   \
    BAR();                 /* BAR_e: all waves' A-reads complete */       \
    if (pre) { STAGE_A(Ac, ktpre); }                                      \
    MFMA_Q(4, 2, bf23);                                                   \
    if (rd) {                                                             \
        if (pre) { VMW(8); } else { VMW(0); }                             \
        BAR();             /* BAR_g: next-buffer stages landed */         \
        READ_A(0, An);     /* 12 boundary reads under MFMA4 drain */      \
        READ_B01(Bn);                                                     \
    }

__global__ __launch_bounds__(512, 2)
void gemm_fused_kernel(char* __restrict__ arena, int N, int M,
                       const float* __restrict__ inv_nn,
                       unsigned* __restrict__ negmax_u) {
    __shared__ __bf16 As[2][256 * 64];   // 2 x 32 KB
    __shared__ __bf16 Bs[2][256 * 64];   // 2 x 32 KB  (total 128 KB)

    // XCD-pinned A-stripe mapping (1 block/CU, 32 CU/XCD, round-robin disp):
    //   xcd = lin&7 owns A-panels 4*xcd..4*xcd+3 (2MB, resident all rounds)
    //   j = lin>>3: round r = j>>5 picks 8 B-panels; u = j&31: 4bm x 8bn
    const int lin = blockIdx.x;
    const int xcd = lin & 7;
    const int j   = lin >> 3;
    const int r   = j >> 5;
    const int u   = j & 31;
    const int bm = ((xcd << 2) + (u & 3)) << 8;
    const int bn = ((r << 3) + (u >> 2)) << 8;

    const int t = threadIdx.x, w = t >> 6, lane = t & 63;
    const int lane16 = lane & 15, lq = lane >> 4;
    const int wm = w >> 2, wn = w & 3;          // 2 M-waves x 4 N-waves

    // ---- staging source offsets (bytes from arena; xor-swizzled octet) ----
    const int l3 = lane >> 3, ol = lane & 7;
    const int og = ol ^ l3;                      // (grow&7)==l3 for all rows
    unsigned srcA[2][2], srcB[2][2];
#pragma unroll
    for (int h = 0; h < 2; h++)
#pragma unroll
      for (int c = 0; c < 2; c++) {
        const int ga = bm + h * 128 + c * 64 + w * 8 + l3;
        srcA[h][c] = ((unsigned)(ga >> 2) << 14) + ((unsigned)(ga & 3) << 11)
                     + 8192u + (unsigned)og * 16u;
        const int gb = N + bn + h * 128 + c * 64 + w * 8 + l3;
        srcB[h][c] = ((unsigned)(gb >> 2) << 14) + ((unsigned)(gb & 3) << 11)
                     + 8192u + (unsigned)og * 16u;
      }

    // ---- fragment read offsets (swizzled octet, elements) ----
    const int sxr = lane16 & 7;
    int koff[2];
#pragma unroll
    for (int kk = 0; kk < 2; kk++) koff[kk] = ((lq + 4 * kk) ^ sxr) * 8;
    const int arow0 = wm * 8192 + lane16 * 64;   // wave's A rows: wm*128+..
    const int brow0 = wn * 4096 + lane16 * 64;   // wave's B rows: wn*64+..

    f32x4_t acc[8][4];
#pragma unroll
    for (int i = 0; i < 8; i++)
#pragma unroll
      for (int j2 = 0; j2 < 4; j2++) acc[i][j2] = (f32x4_t){0.f, 0.f, 0.f, 0.f};

    bf16x8_t af[4][2], bf01[2][2], bf23[2][2];

    __bf16* const A0 = As[0]; __bf16* const A1 = As[1];
    __bf16* const B0 = Bs[0]; __bf16* const B1 = Bs[1];

    // prologue: tiles 0,1 fully staged; tile0 landed; boundary reads issued
    STAGE_A(A0, 0); STAGE_B(B0, 0);
    STAGE_A(A1, 1); STAGE_B(B1, 1);
    VMW(8);
    BAR();
    READ_A(0, A0);
    READ_B01(B0);

    for (int it = 0; it < 8; ++it) {
        const int pre = (it < 7);
        const int k2 = 2 * it + 2, k3 = 2 * it + 3;
        TILE(A0, B0, A1, B1, k2, pre, 1)
        TILE(A1, B1, A0, B0, k3, pre, pre)
    }

    // C/D layout (16x16x32): col = lane16, row = lq*4 + reg
    if (bn < M) {
        // modal half: store G as bf16 into slot front halves
#pragma unroll
        for (int i = 0; i < 8; i++) {
#pragma unroll
            for (int rr = 0; rr < 4; rr++) {
                const int grow = bm + wm * 128 + i * 16 + lq * 4 + rr;
                __bf16* dst = (__bf16*)(arena + ((size_t)grow << 14)) +
                              bn + wn * 64 + lane16;
#pragma unroll
                for (int jj = 0; jj < 4; jj++)
                    dst[jj * 16] = (__bf16)acc[i][jj][rr];
            }
        }
    } else {
        // negatives half: per-row cosine max via atomicMax
        float invn[4];
#pragma unroll
        for (int jj = 0; jj < 4; jj++)
            invn[jj] = inv_nn[(bn - M) + wn * 64 + jj * 16 + lane16];
#pragma unroll
        for (int i = 0; i < 8; i++) {
#pragma unroll
            for (int rr = 0; rr < 4; rr++) {
                float v = acc[i][0][rr] * invn[0];
                v = fmaxf(v, acc[i][1][rr] * invn[1]);
                v = fmaxf(v, acc[i][2][rr] * invn[2]);
                v = fmaxf(v, acc[i][3][rr] * invn[3]);
#pragma unroll
                for (int o = 8; o > 0; o >>= 1)
                    v = fmaxf(v, __shfl_xor(v, o, WAVE));
                if (lane16 == 0)
                    atomicMax(&negmax_u[bm + wm * 128 + i * 16 + lq * 4 + rr],
                              enc_f(v));
            }
        }
    }
}

// ---------------- softmax with fp32 fix-up, 4 rows/block -------------------
#define CUT 2.0f
#define MAXCAND 64
#define SROWS 4

__global__ __launch_bounds__(256)
void softmax_fix_kernel(char* __restrict__ arena, const float* __restrict__ step,
                        const float* __restrict__ modal,
                        const float* __restrict__ ina, const float* __restrict__ inb,
                        float* __restrict__ perstep, float* __restrict__ wout,
                        float* __restrict__ attn) {
    const int row0 = blockIdx.x * SROWS, tid = threadIdx.x;
    const int lane = tid & 63, wv = tid >> 6;

    __shared__ float srow_s[1024];
    __shared__ float red[8];
    __shared__ float bcast[2];
    __shared__ int   cand[MAXCAND];
    __shared__ float exact[MAXCAND];
    __shared__ int   cnt;

    // invn hoisted: same 16KB fp32 vector for every row
    float invn[16];
#pragma unroll
    for (int g = 0; g < 4; g++) {
        const float4 x = *(const float4*)(inb + g * 1024 + tid * 4);
        invn[g * 4 + 0] = x.x; invn[g * 4 + 1] = x.y;
        invn[g * 4 + 2] = x.z; invn[g * 4 + 3] = x.w;
    }
    const float invT = 1.0f / 0.07f;

    for (int rr = 0; rr < SROWS; rr++) {
        const int row = row0 + rr;
        if (tid == 0) cnt = 0;
        ((float4*)srow_s)[tid] = ((const float4*)(step + (size_t)row * 1024))[tid];

        const __bf16* gb = (const __bf16*)(arena + ((size_t)row << 14));
        float vals[16];
#pragma unroll
        for (int g = 0; g < 4; g++) {
            const bf16x4_t v = *(const bf16x4_t*)(gb + g * 1024 + tid * 4);
            vals[g * 4 + 0] = (float)v[0]; vals[g * 4 + 1] = (float)v[1];
            vals[g * 4 + 2] = (float)v[2]; vals[g * 4 + 3] = (float)v[3];
        }

        float dmax = -3.4e38f;
#pragma unroll
        for (int j = 0; j < 16; j++) dmax = fmaxf(dmax, vals[j]);
        float wm = wave_reduce_max(dmax);
        if (lane == 0) red[wv] = wm;
        __syncthreads();   // also covers cnt=0 and srow_s
        if (tid == 0) bcast[0] = fmaxf(fmaxf(red[0], red[1]),
                                       fmaxf(red[2], red[3]));
        __syncthreads();
        const float m0 = bcast[0];

        const float thr = m0 - CUT;
#pragma unroll
        for (int g = 0; g < 4; g++)
#pragma unroll
            for (int u = 0; u < 4; u++) {
                if (vals[g * 4 + u] >= thr) {
                    const int pos = atomicAdd(&cnt, 1);
                    if (pos < MAXCAND) cand[pos] = g * 1024 + tid * 4 + u;
                }
            }
        __syncthreads();
        const int nc = min(cnt, MAXCAND);

        // exact fp32 dots, one candidate per wave
        for (int i = wv; i < nc; i += 4) {
            const float* mrow = modal + (size_t)cand[i] * 1024;
            float p = 0.0f;
#pragma unroll
            for (int q = 0; q < 16; q++) {
                const int idx = lane + q * 64;
                p = fmaf(srow_s[idx], mrow[idx], p);
            }
            p = wave_reduce_sum(p);
            if (lane == 0) exact[i] = p;
        }
        __syncthreads();

        // scatter fix-ups; tid0 computes post-fix max from exact[] alone
        // (valid: non-candidate bf16 vals < m0-CUT < max(exact) >= m0-err)
        for (int i = 0; i < nc; i++) {
            const int c = cand[i];
            if (((c & 1023) >> 2) == tid) vals[(c >> 10) * 4 + (c & 3)] = exact[i];
        }
        if (tid == 0) {
            float mx = -3.4e38f;
            for (int i = 0; i < nc; i++) mx = fmaxf(mx, exact[i]);
            bcast[0] = mx;
        }
        __syncthreads();
        const float mlog = bcast[0] * invT;

        // exp + lsum + cmax in one pass (exp recomputed at write; no evals[])
        float lsum = 0.0f, cmax = -3.4e38f;
#pragma unroll
        for (int j = 0; j < 16; j++) {
            lsum += __expf(vals[j] * invT - mlog);
            cmax = fmaxf(cmax, vals[j] * invn[j]);
        }
        lsum = wave_reduce_sum(lsum);
        float wc = wave_reduce_max(cmax);
        if (lane == 0) { red[wv] = lsum; red[4 + wv] = wc; }
        __syncthreads();
        if (tid == 0) {
            bcast[0] = red[0] + red[1] + red[2] + red[3];
            bcast[1] = fmaxf(fmaxf(red[4], red[5]), fmaxf(red[6], red[7]));
        }
        __syncthreads();
        const float invZ = 1.0f / bcast[0];
        const float cmaxAll = bcast[1];

        float* arow = attn + (size_t)row * 4096;
        float wacc = 0.0f;
#pragma unroll
        for (int g = 0; g < 4; g++) {
            float4 o;
            const float a0 = __expf(vals[g * 4 + 0] * invT - mlog) * invZ;
            const float a1 = __expf(vals[g * 4 + 1] * invT - mlog) * invZ;
            const float a2 = __expf(vals[g * 4 + 2] * invT - mlog) * invZ;
            const float a3 = __expf(vals[g * 4 + 3] * invT - mlog) * invZ;
            o.x = a0; o.y = a1; o.z = a2; o.w = a3;
            *(float4*)(arow + g * 1024 + tid * 4) = o;
            wacc += a0 * vals[g * 4 + 0] * invn[g * 4 + 0];
            wacc += a1 * vals[g * 4 + 1] * invn[g * 4 + 1];
            wacc += a2 * vals[g * 4 + 2] * invn[g * 4 + 2];
            wacc += a3 * vals[g * 4 + 3] * invn[g * 4 + 3];
        }
        wacc = wave_reduce_sum(wacc);
        if (lane == 0) red[wv] = wacc;
        __syncthreads();
        if (tid == 0) {
            const float inv_na = ina[row];
            perstep[row] = cmaxAll * inv_na;
            wout[row] = (red[0] + red[1] + red[2] + red[3]) * inv_na;
        }
        __syncthreads();   // protect srow_s/cnt/red for next row
    }
}

// ---------------- finalize scalars -----------------------------------------
__global__ __launch_bounds__(1024)
void finalize_kernel(const float* __restrict__ perstep, const float* __restrict__ w,
                     const unsigned* __restrict__ negmax_u,
                     const float* __restrict__ ina, float* __restrict__ out,
                     int N, size_t NM) {
    float s_a = 0.0f, s_w = 0.0f, s_n = 0.0f, mn = 3.4e38f;
    for (int i = threadIdx.x; i < N; i += 1024) {
        const float p = perstep[i];
        s_a += p;
        s_w += w[i];
        s_n += dec_f(negmax_u[i]) * ina[i];
        mn = fminf(mn, p);
    }
    s_a = wave_reduce_sum(s_a);
    s_w = wave_reduce_sum(s_w);
    s_n = wave_reduce_sum(s_n);
    mn  = wave_reduce_min(mn);
    __shared__ float ra[16], rw[16], rn[16], rm[16];
    const int lane = threadIdx.x & 63, wv = threadIdx.x >> 6;
    if (lane == 0) { ra[wv] = s_a; rw[wv] = s_w; rn[wv] = s_n; rm[wv] = mn; }
    __syncthreads();
    if (threadIdx.x == 0) {
        float ta = 0, tw = 0, tn = 0, tm = 3.4e38f;
#pragma unroll
        for (int i = 0; i < 16; i++) {
            ta += ra[i]; tw += rw[i]; tn += rn[i]; tm = fminf(tm, rm[i]);
        }
        const float inv = 1.0f / (float)N;
        const float alignment = ta * inv;
        const float weighted  = tw * inv;
        const float neg       = tn * inv;
        const float contrast  = alignment - neg;
        const float margin    = fmaxf(contrast - 0.2f, 0.0f);
        const float overall   = 0.7f * weighted + 0.3f * contrast;
        out[0] = alignment;
        out[1] = weighted;
        float* p = out + 2 + NM;
        p[0] = contrast;
        p[1] = margin;
        p[2] = alignment;   // positive_alignment
        p[3] = neg;
        p[4 + N] = tm;      // min_step_coherence
        p[5 + N] = overall;
    }
}

// ---------------------------------------------------------------------------
extern "C" void kernel_launch(void* const* d_in, const int* in_sizes, int n_in,
                              void* d_out, int out_size, void* d_ws, size_t ws_size,
                              hipStream_t stream) {
    const float* step  = (const float*)d_in[0];
    const float* modal = (const float*)d_in[1];
    const float* negs  = (const float*)d_in[2];
    float* out = (float*)d_out;

    const int K = 1024;
    const int N = in_sizes[0] / K;   // 8192
    const int M = in_sizes[1] / K;   // 4096
    const size_t NM = (size_t)N * (size_t)M;

    float* ina        = (float*)d_ws;          // N
    float* inb        = ina + N;               // M
    float* inn        = inb + M;               // M
    unsigned* negmax  = (unsigned*)(inn + M);  // N
    float* wsum       = (float*)(negmax + N);  // N

    char* arena    = (char*)d_out + 16;
    float* attn    = out + 2;
    float* perstep = out + 2 + NM + 4;

    // 1. convert inputs to bf16 chunks + inverse norms + init atomics
    convert_norms_kernel<<<(N + 2 * M) / 4, 256, 0, stream>>>(
        step, modal, negs, arena, ina, inb, inn, negmax, N, M);

    // 2. fused GEMM (round-14 schedule, XCD-pinned A-stripe mapping)
    const int nblocks = (N >> 8) * ((2 * M) >> 8);   // 32 x 32 = 1024
    gemm_fused_kernel<<<nblocks, 512, 0, stream>>>(arena, N, M, inn, negmax);

    // 3. softmax + exact fp32 fix-up, 4 rows/block
    softmax_fix_kernel<<<N / SROWS, 256, 0, stream>>>(arena, step, modal, ina,
                                                      inb, perstep, wsum, attn);

    // 4. scalars
    finalize_kernel<<<1, 1024, 0, stream>>>(perstep, wsum, negmax, ina, out, N, NM);
}